// Round 9
// baseline (633.407 us; speedup 1.0000x reference)
//
#include <hip/hip_runtime.h>
#include <hip/hip_bf16.h>

#define B_ 32
#define N_ 96
#define D_ 64
#define L_ 5
#define BE_ 24576
#define NN_ 9216
#define BNN_ 294912
#define EPS_ 1e-5f
#define INV_NN (1.0f/9216.0f)

typedef unsigned short u16;
typedef unsigned int u32;
typedef __attribute__((ext_vector_type(8))) short bf16x8;
typedef __attribute__((ext_vector_type(4))) float f32x4;

__device__ __forceinline__ float bf2f(u16 r){ return __uint_as_float(((u32)r) << 16); }
__device__ __forceinline__ u32 f2bf(float f){
  u32 u = __float_as_uint(f);
  return (u + 0x7fffu + ((u >> 16) & 1u)) >> 16;   // RNE
}
__device__ __forceinline__ u32 pack2(float lo, float hi){
  return f2bf(lo) | (f2bf(hi) << 16);
}

// ---------------- scatter: build packed A (last-write-wins via priority) ----------------
__global__ void k_scatter(const int* __restrict__ ei, const int* __restrict__ ea,
                          int* __restrict__ A)
{
  int e = blockIdx.x * 256 + threadIdx.x;
  if (e >= BE_) return;
  int a = ei[e], bnode = ei[BE_ + e];
  int g = a / N_;
  int u = a % N_;
  int v = bnode % N_;
  int lab = ea[e] & 7;
  int base = g * NN_;
  atomicMax(&A[base + u * N_ + v], ((e + 1) << 3) | lab);
  atomicMax(&A[base + v * N_ + u], ((BE_ + e + 1) << 3) | lab);
}

// ---------------- W init (bf16, 4 channels/thread) ----------------
__launch_bounds__(256)
__global__ void k_winit(const int* __restrict__ x, const int* __restrict__ A,
                        const float* __restrict__ nemb, const float* __restrict__ eemb,
                        u16* __restrict__ W)
{
  int gid = blockIdx.x * 256 + threadIdx.x;      // over BNN_*16
  int d = (gid & 15) * 4;
  int p = gid >> 4;
  int b = p / NN_;
  int rem = p % NN_;
  int u = rem / N_;
  int v = rem % N_;
  int xu = x[b * N_ + u], xv = x[b * N_ + v];
  int pk = A[p];
  int lab = pk ? (pk & 7) : 5;
  float4 nu = *(const float4*)(nemb + xu * 64 + d);
  float4 nv = *(const float4*)(nemb + xv * 64 + d);
  float4 ee = *(const float4*)(eemb + lab * 64 + d);
  uint2 o;
  o.x = pack2(nu.x + nv.x + ee.x, nu.y + nv.y + ee.y);
  o.y = pack2(nu.z + nv.z + ee.z, nu.w + nv.w + ee.w);
  ((uint2*)W)[gid] = o;
}

// ---------------- prep: transpose weights to [e][d] bf16 ----------------
__global__ void k_prep(const float* __restrict__ W1, const float* __restrict__ W2,
                       const float* __restrict__ Wm, u16* __restrict__ WT)
{
  int idx = blockIdx.x * 256 + threadIdx.x;   // 15*4096
  if (idx >= 15 * 4096) return;
  int l3 = idx >> 12;
  int r  = idx & 4095;
  int e = r >> 6, d = r & 63;
  int l = l3 / 3, which = l3 % 3;
  const float* s = which == 0 ? W1 : which == 1 ? W2 : Wm;
  WT[idx] = (u16)f2bf(s[l * 4096 + d * 64 + e]);
}

// ---------------- k_ns: reduce stat partials -> finalized (scale,shift) per (b,d) ----------------
__launch_bounds__(128)
__global__ void k_ns(const float* __restrict__ pst, const float* __restrict__ gml,
                     const float* __restrict__ btl, float* __restrict__ nsF)
{
  __shared__ float nsS[128];
  const int b = blockIdx.x;
  const int tid = threadIdx.x;
  const float* p = pst + ((size_t)b * 144) * 128 + tid;
  float a0 = 0.f, a1 = 0.f, a2 = 0.f, a3 = 0.f;
  for (int i = 0; i < 144; i += 4) {
    a0 += p[(size_t)i * 128];
    a1 += p[(size_t)(i + 1) * 128];
    a2 += p[(size_t)(i + 2) * 128];
    a3 += p[(size_t)(i + 3) * 128];
  }
  nsS[tid] = (a0 + a1) + (a2 + a3);
  __syncthreads();
  if (tid < 64) {
    float S1 = nsS[tid], S2 = nsS[64 + tid];
    float mu = S1 * INV_NN;
    float var = fmaf(S2, INV_NN, -mu * mu);
    float s0 = gml[tid] * rsqrtf(var + EPS_);
    nsF[((size_t)b * 64 + tid) * 2]     = s0;
    nsF[((size_t)b * 64 + tid) * 2 + 1] = fmaf(-mu, s0, btl[tid]);
  }
}

// ---------------- fused lin: h1 = relu(nW@W1+b1), g2 = relu(nW@W2+b2)*adj ----------------
__launch_bounds__(256, 8)
__global__ void k_lin2(const u16* __restrict__ W, const u16* __restrict__ WT1,
                       const u16* __restrict__ WT2,
                       const float* __restrict__ b1l, const float* __restrict__ b2l,
                       const int* __restrict__ A, const float* __restrict__ nsF,
                       int use_norm, u16* __restrict__ h1, u16* __restrict__ g2)
{
  __shared__ u16 Cs[64 * 136];
  const int tid = threadIdx.x;
  const int wave = tid >> 6, lane = tid & 63;
  const int lm = lane & 15, lg = lane >> 4;
  const int b = blockIdx.x / 72;
  const int qbase = (blockIdx.x % 72) * 128;

  float sc[2][8], sh[2][8];
  if (use_norm) {
    #pragma unroll
    for (int s = 0; s < 2; ++s) {
      int d0 = s * 32 + lg * 8;
      #pragma unroll
      for (int j = 0; j < 8; j += 2) {
        float4 t = *(const float4*)(nsF + ((size_t)b * 64 + d0 + j) * 2);
        sc[s][j] = t.x; sh[s][j] = t.y; sc[s][j + 1] = t.z; sh[s][j + 1] = t.w;
      }
    }
  } else {
    #pragma unroll
    for (int s = 0; s < 2; ++s)
      #pragma unroll
      for (int j = 0; j < 8; ++j) { sc[s][j] = 1.f; sh[s][j] = 0.f; }
  }

  // B-fragments (normed W rows) + adjacency flags, natural pair order
  bf16x8 bF[2][2];
  int flags[2];
  #pragma unroll
  for (int qt = 0; qt < 2; ++qt) {
    int q = qbase + wave * 32 + qt * 16 + lm;
    const u16* wrow = W + ((size_t)b * NN_ + q) * 64;
    flags[qt] = A[b * NN_ + q];
    #pragma unroll
    for (int s = 0; s < 2; ++s) {
      bf16x8 raw = *(const bf16x8*)(wrow + s * 32 + lg * 8);
      if (use_norm) {
        bf16x8 bb;
        #pragma unroll
        for (int j = 0; j < 8; ++j) {
          float v = bf2f((u16)raw[j]);
          v = fmaxf(fmaf(v, sc[s][j], sh[s][j]), 0.f);
          bb[j] = (short)f2bf(v);
        }
        bF[qt][s] = bb;
      } else {
        bF[qt][s] = raw;
      }
    }
  }

  const f32x4 zf = {0.f, 0.f, 0.f, 0.f};

  // ---- pass 1: h1 (qt-outer: only 4 accumulators live) ----
  {
    bf16x8 aF[4][2];
    #pragma unroll
    for (int et = 0; et < 4; ++et)
      #pragma unroll
      for (int s = 0; s < 2; ++s)
        aF[et][s] = *(const bf16x8*)(WT1 + (et * 16 + lm) * 64 + s * 32 + lg * 8);
    float4 bsv[4];
    #pragma unroll
    for (int et = 0; et < 4; ++et) bsv[et] = *(const float4*)(b1l + et * 16 + lg * 4);
    #pragma unroll
    for (int qt = 0; qt < 2; ++qt) {
      f32x4 acc[4] = {zf, zf, zf, zf};
      #pragma unroll
      for (int s = 0; s < 2; ++s)
        #pragma unroll
        for (int et = 0; et < 4; ++et)
          acc[et] = __builtin_amdgcn_mfma_f32_16x16x32_bf16(aF[et][s], bF[qt][s], acc[et], 0, 0, 0);
      int col = wave * 32 + qt * 16 + lm;
      #pragma unroll
      for (int et = 0; et < 4; ++et) {
        float bv[4] = {bsv[et].x, bsv[et].y, bsv[et].z, bsv[et].w};
        #pragma unroll
        for (int r = 0; r < 4; ++r)
          Cs[(et * 16 + lg * 4 + r) * 136 + col] = (u16)f2bf(fmaxf(acc[et][r] + bv[r], 0.f));
      }
    }
  }
  __syncthreads();
  {
    u16* ob = h1 + (size_t)b * 64 * NN_ + qbase;
    for (int i = tid; i < 1024; i += 256) {
      int e = i >> 4, qc = (i & 15) * 8;
      uint4 val = *(const uint4*)&Cs[e * 136 + qc];
      *(uint4*)(ob + (size_t)e * NN_ + qc) = val;
    }
  }
  __syncthreads();

  // ---- pass 2: g2 (masked), qt-outer ----
  {
    bf16x8 aF[4][2];
    #pragma unroll
    for (int et = 0; et < 4; ++et)
      #pragma unroll
      for (int s = 0; s < 2; ++s)
        aF[et][s] = *(const bf16x8*)(WT2 + (et * 16 + lm) * 64 + s * 32 + lg * 8);
    float4 bsv[4];
    #pragma unroll
    for (int et = 0; et < 4; ++et) bsv[et] = *(const float4*)(b2l + et * 16 + lg * 4);
    #pragma unroll
    for (int qt = 0; qt < 2; ++qt) {
      f32x4 acc[4] = {zf, zf, zf, zf};
      #pragma unroll
      for (int s = 0; s < 2; ++s)
        #pragma unroll
        for (int et = 0; et < 4; ++et)
          acc[et] = __builtin_amdgcn_mfma_f32_16x16x32_bf16(aF[et][s], bF[qt][s], acc[et], 0, 0, 0);
      int col = wave * 32 + qt * 16 + lm;
      #pragma unroll
      for (int et = 0; et < 4; ++et) {
        float bv[4] = {bsv[et].x, bsv[et].y, bsv[et].z, bsv[et].w};
        #pragma unroll
        for (int r = 0; r < 4; ++r) {
          float v = fmaxf(acc[et][r] + bv[r], 0.f);
          if (!flags[qt]) v = 0.f;
          Cs[(et * 16 + lg * 4 + r) * 136 + col] = (u16)f2bf(v);
        }
      }
    }
  }
  __syncthreads();
  {
    u16* ob = g2 + (size_t)b * 64 * NN_ + qbase;
    for (int i = tid; i < 1024; i += 256) {
      int e = i >> 4, qc = (i & 15) * 8;
      uint4 val = *(const uint4*)&Cs[e * 136 + qc];
      *(uint4*)(ob + (size_t)e * NN_ + qc) = val;
    }
  }
}

// ---------------- einsum: per (b,d) 96x96x96; A direct, B via manual LDS transpose ----------------
__launch_bounds__(256, 4)
__global__ void k_einsum(const u16* __restrict__ h1, const u16* __restrict__ g2n,
                         u16* __restrict__ M)
{
  __shared__ u32 Bt[96 * 60];
  u16* Cst = (u16*)Bt;
  const int tid = threadIdx.x;
  const int wave = tid >> 6, lane = tid & 63;
  const int lm = lane & 15, lg = lane >> 4;
  const int bd = blockIdx.x;
  const u16* h1p = h1 + (size_t)bd * NN_;
  const u16* g2p = g2n + (size_t)bd * NN_;
  const int u0 = (wave & 1) * 48, v0 = (wave >> 1) * 48;

  // transpose-stage g2 into Bt
  #pragma unroll
  for (int it = 0; it < 9; ++it) {
    int p = it * 256 + tid;          // [0, 2304): wp = p/48, vh = 2*(p%48)
    int wp = p / 48, vh = (p % 48) * 2;
    u32 a = *(const u32*)(g2p + (2 * wp) * 96 + vh);
    u32 c = *(const u32*)(g2p + (2 * wp + 1) * 96 + vh);
    Bt[vh * 60 + wp]       = (a & 0xffffu) | (c << 16);
    Bt[(vh + 1) * 60 + wp] = (a >> 16) | (c & 0xffff0000u);
  }

  // A fragments direct from global (issued before barrier -> overlap)
  bf16x8 aF[3][3];
  #pragma unroll
  for (int t = 0; t < 3; ++t)
    #pragma unroll
    for (int s = 0; s < 3; ++s)
      aF[t][s] = *(const bf16x8*)(h1p + (u0 + t * 16 + lm) * 96 + s * 32 + lg * 8);
  __syncthreads();

  const f32x4 zf = {0.f, 0.f, 0.f, 0.f};
  f32x4 acc[3][3];
  #pragma unroll
  for (int i = 0; i < 3; ++i)
    #pragma unroll
    for (int j = 0; j < 3; ++j) acc[i][j] = zf;

  // per-s B fragments (only 3 live at a time)
  #pragma unroll
  for (int s = 0; s < 3; ++s) {
    bf16x8 bb[3];
    #pragma unroll
    for (int vt = 0; vt < 3; ++vt)
      bb[vt] = *(const bf16x8*)&Bt[(v0 + vt * 16 + lm) * 60 + s * 16 + lg * 4];
    #pragma unroll
    for (int ut = 0; ut < 3; ++ut)
      #pragma unroll
      for (int vt = 0; vt < 3; ++vt)
        acc[ut][vt] = __builtin_amdgcn_mfma_f32_16x16x32_bf16(aF[ut][s], bb[vt], acc[ut][vt], 0, 0, 0);
  }
  __syncthreads();   // all waves done reading Bt; reuse as C-stage

  #pragma unroll
  for (int ut = 0; ut < 3; ++ut)
    #pragma unroll
    for (int vt = 0; vt < 3; ++vt)
      #pragma unroll
      for (int r = 0; r < 4; ++r)
        Cst[(u0 + ut * 16 + lg * 4 + r) * 104 + v0 + vt * 16 + lm] = (u16)f2bf(acc[ut][vt][r]);
  __syncthreads();
  u16* Mp = M + (size_t)bd * NN_;
  for (int i = tid; i < 1152; i += 256) {
    int u = i / 12, vc = (i % 12) * 8;
    uint4 val = *(const uint4*)&Cst[u * 104 + vc];
    *(uint4*)(Mp + u * 96 + vc) = val;
  }
}

// ---------------- update: W[q][e] = res + (M@Wm)[q][e] + bm; stat partials (no atomics) ----------------
__launch_bounds__(128)
__global__ void k_update(const u16* __restrict__ M, const u16* __restrict__ WmT,
                         const float* __restrict__ bml, u16* __restrict__ W,
                         const float* __restrict__ nsF, int use_norm,
                         float* __restrict__ pst)
{
  __shared__ u16 Mt[64 * 64];
  __shared__ float red[2][128];
  const int tid = threadIdx.x;
  const int wave = tid >> 6, lane = tid & 63;
  const int lm = lane & 15, lg = lane >> 4;
  const int b = blockIdx.x / 144;
  const int qi = blockIdx.x % 144;
  const int qblk = qi * 64;

  // early: Wm fragments (independent of staging)
  bf16x8 aF[4][2];
  #pragma unroll
  for (int et = 0; et < 4; ++et)
    #pragma unroll
    for (int s = 0; s < 2; ++s)
      aF[et][s] = *(const bf16x8*)(WmT + (et * 16 + lm) * 64 + s * 32 + lg * 8);

  // early: W residual rows (prefetched before barrier)
  uint2 wres[2][4];
  #pragma unroll
  for (int qtL = 0; qtL < 2; ++qtL) {
    int qg = qblk + (wave * 2 + qtL) * 16 + lm;
    const u16* Wp = W + ((size_t)b * NN_ + qg) * 64;
    #pragma unroll
    for (int et = 0; et < 4; ++et)
      wres[qtL][et] = *(const uint2*)(Wp + et * 16 + lg * 4);
  }

  // early: finalized norm coefficients
  float scn[4][4], shn[4][4];
  if (use_norm) {
    #pragma unroll
    for (int et = 0; et < 4; ++et) {
      int e0 = et * 16 + lg * 4;
      float4 t0 = *(const float4*)(nsF + ((size_t)b * 64 + e0) * 2);
      float4 t1 = *(const float4*)(nsF + ((size_t)b * 64 + e0) * 2 + 4);
      scn[et][0] = t0.x; shn[et][0] = t0.y; scn[et][1] = t0.z; shn[et][1] = t0.w;
      scn[et][2] = t1.x; shn[et][2] = t1.y; scn[et][3] = t1.z; shn[et][3] = t1.w;
    }
  } else {
    #pragma unroll
    for (int et = 0; et < 4; ++et)
      #pragma unroll
      for (int r = 0; r < 4; ++r) { scn[et][r] = 1.f; shn[et][r] = 0.f; }
  }

  // staging: vectorized M loads, swizzled LDS scatter
  {
    const int dpl = tid >> 1;              // plane 0..63
    const int qob = tid & 1;
    const u16* Mb = M + (size_t)(b * 64 + dpl) * NN_ + qblk;
    #pragma unroll
    for (int t = 0; t < 4; ++t) {
      int qo = qob + t * 2;                // octet 0..7 (q = qo*8 .. +7)
      uint4 v = *(const uint4*)(Mb + qo * 8);
      u32 ws[4] = {v.x, v.y, v.z, v.w};
      #pragma unroll
      for (int h = 0; h < 4; ++h) {
        int j0 = h * 2;
        int q0 = qo * 8 + j0;
        int slot0 = (dpl >> 3) ^ j0 ^ (qo & 7);
        int slot1 = (dpl >> 3) ^ (j0 + 1) ^ (qo & 7);
        Mt[q0 * 64 + slot0 * 8 + (dpl & 7)]       = (u16)(ws[h] & 0xffffu);
        Mt[(q0 + 1) * 64 + slot1 * 8 + (dpl & 7)] = (u16)(ws[h] >> 16);
      }
    }
  }
  __syncthreads();

  const f32x4 zf = {0.f, 0.f, 0.f, 0.f};
  f32x4 acc[2][4];
  #pragma unroll
  for (int i = 0; i < 2; ++i)
    #pragma unroll
    for (int j = 0; j < 4; ++j) acc[i][j] = zf;

  #pragma unroll
  for (int qtL = 0; qtL < 2; ++qtL) {
    int ql = (wave * 2 + qtL) * 16 + lm;
    bf16x8 bF[2];
    #pragma unroll
    for (int s = 0; s < 2; ++s) {
      int slot = (s * 4 + lg) ^ (ql & 7) ^ ((ql >> 3) & 7);
      bF[s] = *(const bf16x8*)&Mt[ql * 64 + slot * 8];
    }
    #pragma unroll
    for (int s = 0; s < 2; ++s)
      #pragma unroll
      for (int et = 0; et < 4; ++et)
        acc[qtL][et] = __builtin_amdgcn_mfma_f32_16x16x32_bf16(aF[et][s], bF[s], acc[qtL][et], 0, 0, 0);
  }

  float s1[4][4], s2[4][4];
  #pragma unroll
  for (int i = 0; i < 4; ++i)
    #pragma unroll
    for (int j = 0; j < 4; ++j) { s1[i][j] = 0.f; s2[i][j] = 0.f; }

  #pragma unroll
  for (int et = 0; et < 4; ++et) {
    int e0 = et * 16 + lg * 4;
    float4 bs = *(const float4*)(bml + e0);
    float bv[4] = {bs.x, bs.y, bs.z, bs.w};
    #pragma unroll
    for (int qtL = 0; qtL < 2; ++qtL) {
      int qg = qblk + (wave * 2 + qtL) * 16 + lm;
      u16* Wp = W + ((size_t)b * NN_ + qg) * 64 + e0;
      uint2 wo = wres[qtL][et];
      float wv[4] = {bf2f((u16)(wo.x & 0xffff)), bf2f((u16)(wo.x >> 16)),
                     bf2f((u16)(wo.y & 0xffff)), bf2f((u16)(wo.y >> 16))};
      float o[4];
      #pragma unroll
      for (int r = 0; r < 4; ++r) {
        float res = use_norm ? fmaxf(fmaf(wv[r], scn[et][r], shn[et][r]), 0.f) : wv[r];
        float val = acc[qtL][et][r] + bv[r] + res;
        o[r] = val;
        s1[et][r] += val;
        s2[et][r] = fmaf(val, val, s2[et][r]);
      }
      uint2 ov;
      ov.x = pack2(o[0], o[1]);
      ov.y = pack2(o[2], o[3]);
      *(uint2*)Wp = ov;
    }
  }

  // wave-local reduce over lm, then block partial write (no atomics)
  #pragma unroll
  for (int et = 0; et < 4; ++et)
    #pragma unroll
    for (int r = 0; r < 4; ++r) {
      float a = s1[et][r], c = s2[et][r];
      a += __shfl_xor(a, 1, 64); a += __shfl_xor(a, 2, 64);
      a += __shfl_xor(a, 4, 64); a += __shfl_xor(a, 8, 64);
      c += __shfl_xor(c, 1, 64); c += __shfl_xor(c, 2, 64);
      c += __shfl_xor(c, 4, 64); c += __shfl_xor(c, 8, 64);
      if (lm == 0) {
        int e = et * 16 + lg * 4 + r;
        red[wave][e]      = a;
        red[wave][64 + e] = c;
      }
    }
  __syncthreads();
  if (tid < 128)
    pst[((size_t)b * 144 + qi) * 128 + tid] = red[0][tid] + red[1][tid];
}

// ---------------- pooling (W bf16; reads finalized nsF) ----------------
__launch_bounds__(256)
__global__ void k_pool(const u16* __restrict__ W,
                       const float* __restrict__ nsF,
                       const float* __restrict__ pw, const float* __restrict__ pb,
                       float* __restrict__ out)
{
  const int b = blockIdx.x / 24;
  const int chunk = blockIdx.x % 24;
  const int tid = threadIdx.x;
  const int e = tid & 63;
  float scl = nsF[((size_t)b * 64 + e) * 2];
  float shf = nsF[((size_t)b * 64 + e) * 2 + 1];
  float pwv = pw[e];
  const u16* base = W + (size_t)b * NN_ * 64 + chunk * 24576;
  float s = 0.f;
  for (int k = 0; k < 96; k++) {
    float w = bf2f(base[k * 256 + tid]);
    s += fmaxf(fmaf(w, scl, shf), 0.f) * pwv;
  }
  for (int o = 32; o; o >>= 1) s += __shfl_down(s, o, 64);
  __shared__ float rs[4];
  if ((tid & 63) == 0) rs[tid >> 6] = s;
  __syncthreads();
  if (tid == 0) {
    float t = rs[0] + rs[1] + rs[2] + rs[3];
    if (chunk == 0) t += pb[0];
    atomicAdd(&out[b], t);
  }
}

extern "C" void kernel_launch(void* const* d_in, const int* in_sizes, int n_in,
                              void* d_out, int out_size, void* d_ws, size_t ws_size,
                              hipStream_t stream) {
  const int*   x    = (const int*)d_in[0];
  const int*   ei   = (const int*)d_in[1];
  const int*   ea   = (const int*)d_in[2];
  const float* nemb = (const float*)d_in[3];
  const float* eemb = (const float*)d_in[4];
  const float* W1   = (const float*)d_in[5];
  const float* b1   = (const float*)d_in[6];
  const float* W2   = (const float*)d_in[7];
  const float* b2   = (const float*)d_in[8];
  const float* Wm   = (const float*)d_in[9];
  const float* bm   = (const float*)d_in[10];
  const float* gm   = (const float*)d_in[11];
  const float* bt   = (const float*)d_in[12];
  const float* pw   = (const float*)d_in[13];
  const float* pb   = (const float*)d_in[14];

  char* ws = (char*)d_ws;
  const size_t OFF_A  = 0;                    // int[BNN]            1,179,648
  const size_t OFF_W  = 1179648;              // bf16[BNN*64]       37,748,736
  const size_t OFF_H1 = 38928384;             // bf16[64B][NN]      37,748,736
  const size_t OFF_G2 = 76677120;             // bf16[64B][NN]      37,748,736
  const size_t OFF_M  = 114425856;            // bf16[64B][NN]      37,748,736
  const size_t OFF_PS = 152174592;            // f32[32][144][128]   2,359,296
  const size_t OFF_NF = 154533888;            // f32[32][64][2]         16,384
  const size_t OFF_WT = 154550272;            // bf16[15][64][64]      122,880
  const size_t NEED   = OFF_WT + 122880;
  if (ws_size < NEED) return;

  int*   A     = (int*)(ws + OFF_A);
  u16*   W     = (u16*)(ws + OFF_W);
  u16*   h1    = (u16*)(ws + OFF_H1);
  u16*   g2n   = (u16*)(ws + OFF_G2);
  u16*   M     = (u16*)(ws + OFF_M);
  float* pst   = (float*)(ws + OFF_PS);
  float* nsF   = (float*)(ws + OFF_NF);
  u16*   WT    = (u16*)(ws + OFF_WT);
  float* out   = (float*)d_out;

  hipMemsetAsync(A, 0, 1179648, stream);
  hipMemsetAsync(out, 0, 32 * sizeof(float), stream);

  k_prep<<<240, 256, 0, stream>>>(W1, W2, Wm, WT);
  k_scatter<<<96, 256, 0, stream>>>(ei, ea, A);
  k_winit<<<18432, 256, 0, stream>>>(x, A, nemb, eemb, W);

  for (int l = 0; l < L_; l++) {
    int un = (l > 0);
    if (un)
      k_ns<<<32, 128, 0, stream>>>(pst, gm + (l - 1) * 64, bt + (l - 1) * 64, nsF);
    k_lin2<<<2304, 256, 0, stream>>>(W, WT + (l * 3 + 0) * 4096, WT + (l * 3 + 1) * 4096,
                                     b1 + l * 64, b2 + l * 64, A, nsF, un, h1, g2n);
    k_einsum<<<2048, 256, 0, stream>>>(h1, g2n, M);
    k_update<<<4608, 128, 0, stream>>>(M, WT + (l * 3 + 2) * 4096, bm + l * 64, W,
                                       nsF, un, pst);
  }
  k_ns<<<32, 128, 0, stream>>>(pst, gm + 4 * 64, bt + 4 * 64, nsF);
  k_pool<<<768, 256, 0, stream>>>(W, nsF, pw, pb, out);
}

// Round 10
// 592.883 us; speedup vs baseline: 1.0684x; 1.0684x over previous
//
#include <hip/hip_runtime.h>
#include <hip/hip_bf16.h>

#define B_ 32
#define N_ 96
#define D_ 64
#define L_ 5
#define BE_ 24576
#define NN_ 9216
#define BNN_ 294912
#define EPS_ 1e-5f
#define INV_NN (1.0f/9216.0f)

typedef unsigned short u16;
typedef unsigned int u32;
typedef __attribute__((ext_vector_type(8))) short bf16x8;
typedef __attribute__((ext_vector_type(4))) float f32x4;

__device__ __forceinline__ float bf2f(u16 r){ return __uint_as_float(((u32)r) << 16); }
__device__ __forceinline__ u32 f2bf(float f){
  u32 u = __float_as_uint(f);
  return (u + 0x7fffu + ((u >> 16) & 1u)) >> 16;   // RNE
}
__device__ __forceinline__ u32 pack2(float lo, float hi){
  return f2bf(lo) | (f2bf(hi) << 16);
}

// ---------------- scatter: build packed A (last-write-wins via priority) ----------------
__global__ void k_scatter(const int* __restrict__ ei, const int* __restrict__ ea,
                          int* __restrict__ A)
{
  int e = blockIdx.x * 256 + threadIdx.x;
  if (e >= BE_) return;
  int a = ei[e], bnode = ei[BE_ + e];
  int g = a / N_;
  int u = a % N_;
  int v = bnode % N_;
  int lab = ea[e] & 7;
  int base = g * NN_;
  atomicMax(&A[base + u * N_ + v], ((e + 1) << 3) | lab);
  atomicMax(&A[base + v * N_ + u], ((BE_ + e + 1) << 3) | lab);
}

// ---------------- W init (bf16, 4 channels/thread) ----------------
__launch_bounds__(256)
__global__ void k_winit(const int* __restrict__ x, const int* __restrict__ A,
                        const float* __restrict__ nemb, const float* __restrict__ eemb,
                        u16* __restrict__ W)
{
  int gid = blockIdx.x * 256 + threadIdx.x;      // over BNN_*16
  int d = (gid & 15) * 4;
  int p = gid >> 4;
  int b = p / NN_;
  int rem = p % NN_;
  int u = rem / N_;
  int v = rem % N_;
  int xu = x[b * N_ + u], xv = x[b * N_ + v];
  int pk = A[p];
  int lab = pk ? (pk & 7) : 5;
  float4 nu = *(const float4*)(nemb + xu * 64 + d);
  float4 nv = *(const float4*)(nemb + xv * 64 + d);
  float4 ee = *(const float4*)(eemb + lab * 64 + d);
  uint2 o;
  o.x = pack2(nu.x + nv.x + ee.x, nu.y + nv.y + ee.y);
  o.y = pack2(nu.z + nv.z + ee.z, nu.w + nv.w + ee.w);
  ((uint2*)W)[gid] = o;
}

// ---------------- prep: transpose weights to [e][d] bf16 ----------------
__global__ void k_prep(const float* __restrict__ W1, const float* __restrict__ W2,
                       const float* __restrict__ Wm, u16* __restrict__ WT)
{
  int idx = blockIdx.x * 256 + threadIdx.x;   // 15*4096
  if (idx >= 15 * 4096) return;
  int l3 = idx >> 12;
  int r  = idx & 4095;
  int e = r >> 6, d = r & 63;
  int l = l3 / 3, which = l3 % 3;
  const float* s = which == 0 ? W1 : which == 1 ? W2 : Wm;
  WT[idx] = (u16)f2bf(s[l * 4096 + d * 64 + e]);
}

// ---------------- k_ns: reduce stat partials -> finalized (scale,shift) per (b,d) ----------------
__launch_bounds__(1024)
__global__ void k_ns(const float* __restrict__ pst, const float* __restrict__ gml,
                     const float* __restrict__ btl, float* __restrict__ nsF)
{
  __shared__ float part[8][128];
  const int b = blockIdx.x;
  const int tid = threadIdx.x;
  const int grp = tid >> 7, idx = tid & 127;
  const float* p = pst + ((size_t)b * 144 + grp) * 128 + idx;
  float a0 = 0.f, a1 = 0.f;
  #pragma unroll
  for (int k = 0; k < 18; k += 2) {
    a0 += p[(size_t)k * 1024];
    a1 += p[(size_t)(k + 1) * 1024];
  }
  part[grp][idx] = a0 + a1;
  __syncthreads();
  if (tid < 128) {
    float s = 0.f;
    #pragma unroll
    for (int g = 0; g < 8; ++g) s += part[g][tid];
    part[0][tid] = s;
  }
  __syncthreads();
  if (tid < 64) {
    float S1 = part[0][tid], S2 = part[0][64 + tid];
    float mu = S1 * INV_NN;
    float var = fmaf(S2, INV_NN, -mu * mu);
    float s0 = gml[tid] * rsqrtf(var + EPS_);
    nsF[((size_t)b * 64 + tid) * 2]     = s0;
    nsF[((size_t)b * 64 + tid) * 2 + 1] = fmaf(-mu, s0, btl[tid]);
  }
}

// ---------------- fused lin: h1 = relu(nW@W1+b1), g2 = relu(nW@W2+b2)*adj ----------------
__launch_bounds__(256)
__global__ void k_lin2(const u16* __restrict__ W, const u16* __restrict__ WT1,
                       const u16* __restrict__ WT2,
                       const float* __restrict__ b1l, const float* __restrict__ b2l,
                       const int* __restrict__ A, const float* __restrict__ nsF,
                       int use_norm, u16* __restrict__ h1, u16* __restrict__ g2)
{
  __shared__ u16 Cs[64 * 136];
  const int tid = threadIdx.x;
  const int wave = tid >> 6, lane = tid & 63;
  const int lm = lane & 15, lg = lane >> 4;
  const int b = blockIdx.x / 72;
  const int qbase = (blockIdx.x % 72) * 128;

  float sc[2][8], sh[2][8];
  if (use_norm) {
    #pragma unroll
    for (int s = 0; s < 2; ++s) {
      int d0 = s * 32 + lg * 8;
      #pragma unroll
      for (int j = 0; j < 8; j += 2) {
        float4 t = *(const float4*)(nsF + ((size_t)b * 64 + d0 + j) * 2);
        sc[s][j] = t.x; sh[s][j] = t.y; sc[s][j + 1] = t.z; sh[s][j + 1] = t.w;
      }
    }
  } else {
    #pragma unroll
    for (int s = 0; s < 2; ++s)
      #pragma unroll
      for (int j = 0; j < 8; ++j) { sc[s][j] = 1.f; sh[s][j] = 0.f; }
  }

  // B-fragments (normed W rows) + adjacency flags, natural pair order
  bf16x8 bF[2][2];
  int flags[2];
  #pragma unroll
  for (int qt = 0; qt < 2; ++qt) {
    int q = qbase + wave * 32 + qt * 16 + lm;
    const u16* wrow = W + ((size_t)b * NN_ + q) * 64;
    flags[qt] = A[b * NN_ + q];
    #pragma unroll
    for (int s = 0; s < 2; ++s) {
      bf16x8 raw = *(const bf16x8*)(wrow + s * 32 + lg * 8);
      if (use_norm) {
        bf16x8 bb;
        #pragma unroll
        for (int j = 0; j < 8; ++j) {
          float v = bf2f((u16)raw[j]);
          v = fmaxf(fmaf(v, sc[s][j], sh[s][j]), 0.f);
          bb[j] = (short)f2bf(v);
        }
        bF[qt][s] = bb;
      } else {
        bF[qt][s] = raw;
      }
    }
  }

  const f32x4 zf = {0.f, 0.f, 0.f, 0.f};

  // ---- pass 1: h1 (qt-outer: only 4 accumulators live) ----
  {
    bf16x8 aF[4][2];
    #pragma unroll
    for (int et = 0; et < 4; ++et)
      #pragma unroll
      for (int s = 0; s < 2; ++s)
        aF[et][s] = *(const bf16x8*)(WT1 + (et * 16 + lm) * 64 + s * 32 + lg * 8);
    float4 bsv[4];
    #pragma unroll
    for (int et = 0; et < 4; ++et) bsv[et] = *(const float4*)(b1l + et * 16 + lg * 4);
    #pragma unroll
    for (int qt = 0; qt < 2; ++qt) {
      f32x4 acc[4] = {zf, zf, zf, zf};
      #pragma unroll
      for (int s = 0; s < 2; ++s)
        #pragma unroll
        for (int et = 0; et < 4; ++et)
          acc[et] = __builtin_amdgcn_mfma_f32_16x16x32_bf16(aF[et][s], bF[qt][s], acc[et], 0, 0, 0);
      int col = wave * 32 + qt * 16 + lm;
      #pragma unroll
      for (int et = 0; et < 4; ++et) {
        float bv[4] = {bsv[et].x, bsv[et].y, bsv[et].z, bsv[et].w};
        #pragma unroll
        for (int r = 0; r < 4; ++r)
          Cs[(et * 16 + lg * 4 + r) * 136 + col] = (u16)f2bf(fmaxf(acc[et][r] + bv[r], 0.f));
      }
    }
  }
  __syncthreads();
  {
    u16* ob = h1 + (size_t)b * 64 * NN_ + qbase;
    for (int i = tid; i < 1024; i += 256) {
      int e = i >> 4, qc = (i & 15) * 8;
      uint4 val = *(const uint4*)&Cs[e * 136 + qc];
      *(uint4*)(ob + (size_t)e * NN_ + qc) = val;
    }
  }
  __syncthreads();

  // ---- pass 2: g2 (masked), qt-outer ----
  {
    bf16x8 aF[4][2];
    #pragma unroll
    for (int et = 0; et < 4; ++et)
      #pragma unroll
      for (int s = 0; s < 2; ++s)
        aF[et][s] = *(const bf16x8*)(WT2 + (et * 16 + lm) * 64 + s * 32 + lg * 8);
    float4 bsv[4];
    #pragma unroll
    for (int et = 0; et < 4; ++et) bsv[et] = *(const float4*)(b2l + et * 16 + lg * 4);
    #pragma unroll
    for (int qt = 0; qt < 2; ++qt) {
      f32x4 acc[4] = {zf, zf, zf, zf};
      #pragma unroll
      for (int s = 0; s < 2; ++s)
        #pragma unroll
        for (int et = 0; et < 4; ++et)
          acc[et] = __builtin_amdgcn_mfma_f32_16x16x32_bf16(aF[et][s], bF[qt][s], acc[et], 0, 0, 0);
      int col = wave * 32 + qt * 16 + lm;
      #pragma unroll
      for (int et = 0; et < 4; ++et) {
        float bv[4] = {bsv[et].x, bsv[et].y, bsv[et].z, bsv[et].w};
        #pragma unroll
        for (int r = 0; r < 4; ++r) {
          float v = fmaxf(acc[et][r] + bv[r], 0.f);
          if (!flags[qt]) v = 0.f;
          Cs[(et * 16 + lg * 4 + r) * 136 + col] = (u16)f2bf(v);
        }
      }
    }
  }
  __syncthreads();
  {
    u16* ob = g2 + (size_t)b * 64 * NN_ + qbase;
    for (int i = tid; i < 1024; i += 256) {
      int e = i >> 4, qc = (i & 15) * 8;
      uint4 val = *(const uint4*)&Cs[e * 136 + qc];
      *(uint4*)(ob + (size_t)e * NN_ + qc) = val;
    }
  }
}

// ---------------- einsum: per (b,d) 96x96x96; A direct, B via manual LDS transpose ----------------
__launch_bounds__(256, 4)
__global__ void k_einsum(const u16* __restrict__ h1, const u16* __restrict__ g2n,
                         u16* __restrict__ M)
{
  __shared__ u32 Bt[96 * 60];
  u16* Cst = (u16*)Bt;
  const int tid = threadIdx.x;
  const int wave = tid >> 6, lane = tid & 63;
  const int lm = lane & 15, lg = lane >> 4;
  const int bd = blockIdx.x;
  const u16* h1p = h1 + (size_t)bd * NN_;
  const u16* g2p = g2n + (size_t)bd * NN_;
  const int u0 = (wave & 1) * 48, v0 = (wave >> 1) * 48;

  // transpose-stage g2 into Bt
  #pragma unroll
  for (int it = 0; it < 9; ++it) {
    int p = it * 256 + tid;          // [0, 2304): wp = p/48, vh = 2*(p%48)
    int wp = p / 48, vh = (p % 48) * 2;
    u32 a = *(const u32*)(g2p + (2 * wp) * 96 + vh);
    u32 c = *(const u32*)(g2p + (2 * wp + 1) * 96 + vh);
    Bt[vh * 60 + wp]       = (a & 0xffffu) | (c << 16);
    Bt[(vh + 1) * 60 + wp] = (a >> 16) | (c & 0xffff0000u);
  }

  // A fragments direct from global (issued before barrier -> overlap)
  bf16x8 aF[3][3];
  #pragma unroll
  for (int t = 0; t < 3; ++t)
    #pragma unroll
    for (int s = 0; s < 3; ++s)
      aF[t][s] = *(const bf16x8*)(h1p + (u0 + t * 16 + lm) * 96 + s * 32 + lg * 8);
  __syncthreads();

  const f32x4 zf = {0.f, 0.f, 0.f, 0.f};
  f32x4 acc[3][3];
  #pragma unroll
  for (int i = 0; i < 3; ++i)
    #pragma unroll
    for (int j = 0; j < 3; ++j) acc[i][j] = zf;

  // per-s B fragments (only 3 live at a time)
  #pragma unroll
  for (int s = 0; s < 3; ++s) {
    bf16x8 bb[3];
    #pragma unroll
    for (int vt = 0; vt < 3; ++vt)
      bb[vt] = *(const bf16x8*)&Bt[(v0 + vt * 16 + lm) * 60 + s * 16 + lg * 4];
    #pragma unroll
    for (int ut = 0; ut < 3; ++ut)
      #pragma unroll
      for (int vt = 0; vt < 3; ++vt)
        acc[ut][vt] = __builtin_amdgcn_mfma_f32_16x16x32_bf16(aF[ut][s], bb[vt], acc[ut][vt], 0, 0, 0);
  }
  __syncthreads();   // all waves done reading Bt; reuse as C-stage

  #pragma unroll
  for (int ut = 0; ut < 3; ++ut)
    #pragma unroll
    for (int vt = 0; vt < 3; ++vt)
      #pragma unroll
      for (int r = 0; r < 4; ++r)
        Cst[(u0 + ut * 16 + lg * 4 + r) * 104 + v0 + vt * 16 + lm] = (u16)f2bf(acc[ut][vt][r]);
  __syncthreads();
  u16* Mp = M + (size_t)bd * NN_;
  for (int i = tid; i < 1152; i += 256) {
    int u = i / 12, vc = (i % 12) * 8;
    uint4 val = *(const uint4*)&Cst[u * 104 + vc];
    *(uint4*)(Mp + u * 96 + vc) = val;
  }
}

// ---------------- update: W[q][e] = res + (M@Wm)[q][e] + bm; stat partials (no atomics) ----------------
__launch_bounds__(128)
__global__ void k_update(const u16* __restrict__ M, const u16* __restrict__ WmT,
                         const float* __restrict__ bml, u16* __restrict__ W,
                         const float* __restrict__ nsF, int use_norm,
                         float* __restrict__ pst)
{
  __shared__ u16 Mt[64 * 64];
  __shared__ float red[2][128];
  const int tid = threadIdx.x;
  const int wave = tid >> 6, lane = tid & 63;
  const int lm = lane & 15, lg = lane >> 4;
  const int b = blockIdx.x / 144;
  const int qi = blockIdx.x % 144;
  const int qblk = qi * 64;

  // early: Wm fragments (independent of staging)
  bf16x8 aF[4][2];
  #pragma unroll
  for (int et = 0; et < 4; ++et)
    #pragma unroll
    for (int s = 0; s < 2; ++s)
      aF[et][s] = *(const bf16x8*)(WmT + (et * 16 + lm) * 64 + s * 32 + lg * 8);

  // early: W residual rows (prefetched before barrier)
  uint2 wres[2][4];
  #pragma unroll
  for (int qtL = 0; qtL < 2; ++qtL) {
    int qg = qblk + (wave * 2 + qtL) * 16 + lm;
    const u16* Wp = W + ((size_t)b * NN_ + qg) * 64;
    #pragma unroll
    for (int et = 0; et < 4; ++et)
      wres[qtL][et] = *(const uint2*)(Wp + et * 16 + lg * 4);
  }

  // early: finalized norm coefficients
  float scn[4][4], shn[4][4];
  if (use_norm) {
    #pragma unroll
    for (int et = 0; et < 4; ++et) {
      int e0 = et * 16 + lg * 4;
      float4 t0 = *(const float4*)(nsF + ((size_t)b * 64 + e0) * 2);
      float4 t1 = *(const float4*)(nsF + ((size_t)b * 64 + e0) * 2 + 4);
      scn[et][0] = t0.x; shn[et][0] = t0.y; scn[et][1] = t0.z; shn[et][1] = t0.w;
      scn[et][2] = t1.x; shn[et][2] = t1.y; scn[et][3] = t1.z; shn[et][3] = t1.w;
    }
  } else {
    #pragma unroll
    for (int et = 0; et < 4; ++et)
      #pragma unroll
      for (int r = 0; r < 4; ++r) { scn[et][r] = 1.f; shn[et][r] = 0.f; }
  }

  // staging: vectorized M loads, swizzled LDS scatter
  {
    const int dpl = tid >> 1;              // plane 0..63
    const int qob = tid & 1;
    const u16* Mb = M + (size_t)(b * 64 + dpl) * NN_ + qblk;
    #pragma unroll
    for (int t = 0; t < 4; ++t) {
      int qo = qob + t * 2;                // octet 0..7 (q = qo*8 .. +7)
      uint4 v = *(const uint4*)(Mb + qo * 8);
      u32 ws[4] = {v.x, v.y, v.z, v.w};
      #pragma unroll
      for (int h = 0; h < 4; ++h) {
        int j0 = h * 2;
        int q0 = qo * 8 + j0;
        int slot0 = (dpl >> 3) ^ j0 ^ (qo & 7);
        int slot1 = (dpl >> 3) ^ (j0 + 1) ^ (qo & 7);
        Mt[q0 * 64 + slot0 * 8 + (dpl & 7)]       = (u16)(ws[h] & 0xffffu);
        Mt[(q0 + 1) * 64 + slot1 * 8 + (dpl & 7)] = (u16)(ws[h] >> 16);
      }
    }
  }
  __syncthreads();

  const f32x4 zf = {0.f, 0.f, 0.f, 0.f};
  f32x4 acc[2][4];
  #pragma unroll
  for (int i = 0; i < 2; ++i)
    #pragma unroll
    for (int j = 0; j < 4; ++j) acc[i][j] = zf;

  #pragma unroll
  for (int qtL = 0; qtL < 2; ++qtL) {
    int ql = (wave * 2 + qtL) * 16 + lm;
    bf16x8 bF[2];
    #pragma unroll
    for (int s = 0; s < 2; ++s) {
      int slot = (s * 4 + lg) ^ (ql & 7) ^ ((ql >> 3) & 7);
      bF[s] = *(const bf16x8*)&Mt[ql * 64 + slot * 8];
    }
    #pragma unroll
    for (int s = 0; s < 2; ++s)
      #pragma unroll
      for (int et = 0; et < 4; ++et)
        acc[qtL][et] = __builtin_amdgcn_mfma_f32_16x16x32_bf16(aF[et][s], bF[s], acc[qtL][et], 0, 0, 0);
  }

  float s1[4][4], s2[4][4];
  #pragma unroll
  for (int i = 0; i < 4; ++i)
    #pragma unroll
    for (int j = 0; j < 4; ++j) { s1[i][j] = 0.f; s2[i][j] = 0.f; }

  #pragma unroll
  for (int et = 0; et < 4; ++et) {
    int e0 = et * 16 + lg * 4;
    float4 bs = *(const float4*)(bml + e0);
    float bv[4] = {bs.x, bs.y, bs.z, bs.w};
    #pragma unroll
    for (int qtL = 0; qtL < 2; ++qtL) {
      int qg = qblk + (wave * 2 + qtL) * 16 + lm;
      u16* Wp = W + ((size_t)b * NN_ + qg) * 64 + e0;
      uint2 wo = wres[qtL][et];
      float wv[4] = {bf2f((u16)(wo.x & 0xffff)), bf2f((u16)(wo.x >> 16)),
                     bf2f((u16)(wo.y & 0xffff)), bf2f((u16)(wo.y >> 16))};
      float o[4];
      #pragma unroll
      for (int r = 0; r < 4; ++r) {
        float res = use_norm ? fmaxf(fmaf(wv[r], scn[et][r], shn[et][r]), 0.f) : wv[r];
        float val = acc[qtL][et][r] + bv[r] + res;
        o[r] = val;
        s1[et][r] += val;
        s2[et][r] = fmaf(val, val, s2[et][r]);
      }
      uint2 ov;
      ov.x = pack2(o[0], o[1]);
      ov.y = pack2(o[2], o[3]);
      *(uint2*)Wp = ov;
    }
  }

  // wave-local reduce over lm, then block partial write (no atomics)
  #pragma unroll
  for (int et = 0; et < 4; ++et)
    #pragma unroll
    for (int r = 0; r < 4; ++r) {
      float a = s1[et][r], c = s2[et][r];
      a += __shfl_xor(a, 1, 64); a += __shfl_xor(a, 2, 64);
      a += __shfl_xor(a, 4, 64); a += __shfl_xor(a, 8, 64);
      c += __shfl_xor(c, 1, 64); c += __shfl_xor(c, 2, 64);
      c += __shfl_xor(c, 4, 64); c += __shfl_xor(c, 8, 64);
      if (lm == 0) {
        int e = et * 16 + lg * 4 + r;
        red[wave][e]      = a;
        red[wave][64 + e] = c;
      }
    }
  __syncthreads();
  if (tid < 128)
    pst[((size_t)b * 144 + qi) * 128 + tid] = red[0][tid] + red[1][tid];
}

// ---------------- pooling (W bf16; reads finalized nsF) ----------------
__launch_bounds__(256)
__global__ void k_pool(const u16* __restrict__ W,
                       const float* __restrict__ nsF,
                       const float* __restrict__ pw, const float* __restrict__ pb,
                       float* __restrict__ out)
{
  const int b = blockIdx.x / 24;
  const int chunk = blockIdx.x % 24;
  const int tid = threadIdx.x;
  const int e = tid & 63;
  float scl = nsF[((size_t)b * 64 + e) * 2];
  float shf = nsF[((size_t)b * 64 + e) * 2 + 1];
  float pwv = pw[e];
  const u16* base = W + (size_t)b * NN_ * 64 + chunk * 24576;
  float s = 0.f;
  for (int k = 0; k < 96; k++) {
    float w = bf2f(base[k * 256 + tid]);
    s += fmaxf(fmaf(w, scl, shf), 0.f) * pwv;
  }
  for (int o = 32; o; o >>= 1) s += __shfl_down(s, o, 64);
  __shared__ float rs[4];
  if ((tid & 63) == 0) rs[tid >> 6] = s;
  __syncthreads();
  if (tid == 0) {
    float t = rs[0] + rs[1] + rs[2] + rs[3];
    if (chunk == 0) t += pb[0];
    atomicAdd(&out[b], t);
  }
}

extern "C" void kernel_launch(void* const* d_in, const int* in_sizes, int n_in,
                              void* d_out, int out_size, void* d_ws, size_t ws_size,
                              hipStream_t stream) {
  const int*   x    = (const int*)d_in[0];
  const int*   ei   = (const int*)d_in[1];
  const int*   ea   = (const int*)d_in[2];
  const float* nemb = (const float*)d_in[3];
  const float* eemb = (const float*)d_in[4];
  const float* W1   = (const float*)d_in[5];
  const float* b1   = (const float*)d_in[6];
  const float* W2   = (const float*)d_in[7];
  const float* b2   = (const float*)d_in[8];
  const float* Wm   = (const float*)d_in[9];
  const float* bm   = (const float*)d_in[10];
  const float* gm   = (const float*)d_in[11];
  const float* bt   = (const float*)d_in[12];
  const float* pw   = (const float*)d_in[13];
  const float* pb   = (const float*)d_in[14];

  char* ws = (char*)d_ws;
  const size_t OFF_A  = 0;                    // int[BNN]            1,179,648
  const size_t OFF_W  = 1179648;              // bf16[BNN*64]       37,748,736
  const size_t OFF_H1 = 38928384;             // bf16[64B][NN]      37,748,736
  const size_t OFF_G2 = 76677120;             // bf16[64B][NN]      37,748,736
  const size_t OFF_M  = 114425856;            // bf16[64B][NN]      37,748,736
  const size_t OFF_PS = 152174592;            // f32[32][144][128]   2,359,296
  const size_t OFF_NF = 154533888;            // f32[32][64][2]         16,384
  const size_t OFF_WT = 154550272;            // bf16[15][64][64]      122,880
  const size_t NEED   = OFF_WT + 122880;
  if (ws_size < NEED) return;

  int*   A     = (int*)(ws + OFF_A);
  u16*   W     = (u16*)(ws + OFF_W);
  u16*   h1    = (u16*)(ws + OFF_H1);
  u16*   g2n   = (u16*)(ws + OFF_G2);
  u16*   M     = (u16*)(ws + OFF_M);
  float* pst   = (float*)(ws + OFF_PS);
  float* nsF   = (float*)(ws + OFF_NF);
  u16*   WT    = (u16*)(ws + OFF_WT);
  float* out   = (float*)d_out;

  hipMemsetAsync(A, 0, 1179648, stream);
  hipMemsetAsync(out, 0, 32 * sizeof(float), stream);

  k_prep<<<240, 256, 0, stream>>>(W1, W2, Wm, WT);
  k_scatter<<<96, 256, 0, stream>>>(ei, ea, A);
  k_winit<<<18432, 256, 0, stream>>>(x, A, nemb, eemb, W);

  for (int l = 0; l < L_; l++) {
    int un = (l > 0);
    if (un)
      k_ns<<<32, 1024, 0, stream>>>(pst, gm + (l - 1) * 64, bt + (l - 1) * 64, nsF);
    k_lin2<<<2304, 256, 0, stream>>>(W, WT + (l * 3 + 0) * 4096, WT + (l * 3 + 1) * 4096,
                                     b1 + l * 64, b2 + l * 64, A, nsF, un, h1, g2n);
    k_einsum<<<2048, 256, 0, stream>>>(h1, g2n, M);
    k_update<<<4608, 128, 0, stream>>>(M, WT + (l * 3 + 2) * 4096, bm + l * 64, W,
                                       nsF, un, pst);
  }
  k_ns<<<32, 1024, 0, stream>>>(pst, gm + 4 * 64, bt + 4 * 64, nsF);
  k_pool<<<768, 256, 0, stream>>>(W, nsF, pw, pb, out);
}